// Round 10
// baseline (73.659 us; speedup 1.0000x reference)
//
#include <hip/hip_runtime.h>
#include <math.h>

// L = diag((W+W^T).sum(1)) - (W+W^T), cotangent weights per face.
// 3-node pipeline, no 268MB memset:
//   node 1: memset 64KB (cnt + diag) in ws
//   node 2: bin_faces - per-face cot weights, append (col,-v) pairs into
//           per-row buckets in ws (L2-resident), diag atomicAdds
//   node 3: fill - ONE ROW PER BLOCK, near-pure store kernel: stage <=65
//           entries in LDS, each thread switch-accumulates its hits into
//           32 registers (dups accumulate => no dedup), then 8 coalesced
//           NONTEMPORAL float4 stores (L2-bypass, the single change vs R9:
//           isolating whether streaming stores are fillBuffer's ~7TB/s trick).

#define CAP 64   // bucket entries/row; mean ~13, P(>64) astronomically small

typedef float v4f __attribute__((ext_vector_type(4)));

__device__ __forceinline__ void cot_weights(const float* __restrict__ V,
                                            int i0, int i1, int i2,
                                            float& c0, float& c1, float& c2) {
    const float ax = V[i0 * 3 + 0], ay = V[i0 * 3 + 1], az = V[i0 * 3 + 2];
    const float bx = V[i1 * 3 + 0], by = V[i1 * 3 + 1], bz = V[i1 * 3 + 2];
    const float cx = V[i2 * 3 + 0], cy = V[i2 * 3 + 1], cz = V[i2 * 3 + 2];

    float dx, dy, dz, d2;
    dx = bx - cx; dy = by - cy; dz = bz - cz;
    d2 = dx * dx + dy * dy + dz * dz;
    const float l1 = (d2 > 0.0f) ? sqrtf(d2) : 0.0f;
    dx = cx - ax; dy = cy - ay; dz = cz - az;
    d2 = dx * dx + dy * dy + dz * dz;
    const float l2 = (d2 > 0.0f) ? sqrtf(d2) : 0.0f;
    dx = ax - bx; dy = ay - by; dz = az - bz;
    d2 = dx * dx + dy * dy + dz * dz;
    const float l3 = (d2 > 0.0f) ? sqrtf(d2) : 0.0f;

    const float sp = (l1 + l2 + l3) * 0.5f;
    const float s  = sp * (sp - l1) * (sp - l2) * (sp - l3);
    const float A  = (s > 0.0f) ? 2.0f * sqrtf(s) : 1.0f;

    c0 = ((l2 * l2 + l3 * l3 - l1 * l1) / A) * 0.25f; // (r=i1, c=i2)
    c1 = ((l1 * l1 + l3 * l3 - l2 * l2) / A) * 0.25f; // (r=i2, c=i0)
    c2 = ((l1 * l1 + l2 * l2 - l3 * l3) / A) * 0.25f; // (r=i0, c=i1)
}

__device__ __forceinline__ void read_face(const int* __restrict__ Fw, int f,
                                          bool is64, int& i0, int& i1, int& i2) {
    if (is64) { i0 = Fw[f * 6]; i1 = Fw[f * 6 + 2]; i2 = Fw[f * 6 + 4]; }
    else      { i0 = Fw[f * 3]; i1 = Fw[f * 3 + 1]; i2 = Fw[f * 3 + 2]; }
}

// ws layout (words): cnt[8192] | diag[8192] | pairs[8192*CAP*2] (col,val)
__global__ __launch_bounds__(256) void bin_faces_kernel(
        const float* __restrict__ V, const int* __restrict__ Fw,
        int* __restrict__ cnt, float* __restrict__ diag,
        int* __restrict__ pairs, int nF) {
    const int f = blockIdx.x * 256 + threadIdx.x;
    if (f >= nF) return;

    const bool is64 = (Fw[1] == 0) && (Fw[3] == 0) && (Fw[5] == 0) &&
                      (Fw[7] == 0) && (Fw[9] == 0) && (Fw[11] == 0);

    int i0, i1, i2;
    read_face(Fw, f, is64, i0, i1, i2);
    float c0, c1, c2;
    cot_weights(V, i0, i1, i2, c0, c1, c2);

    const int rr_[3] = {i1, i2, i0};
    const int cc_[3] = {i2, i0, i1};
    const float vv_[3] = {c0, c1, c2};
#pragma unroll
    for (int t = 0; t < 3; ++t) {
        const int r = rr_[t], c = cc_[t];
        const float v = vv_[t];
        int s = atomicAdd(&cnt[r], 1);
        if (s < CAP) {
            int* p = pairs + (size_t)(r * CAP + s) * 2;
            p[0] = c; ((float*)p)[1] = -v;
        }
        s = atomicAdd(&cnt[c], 1);
        if (s < CAP) {
            int* p = pairs + (size_t)(c * CAP + s) * 2;
            p[0] = r; ((float*)p)[1] = -v;
        }
        atomicAdd(&diag[r], v);
        atomicAdd(&diag[c], v);
    }
}

// One row (8192 floats) per block; N must be 8192.
__global__ __launch_bounds__(256) void fill_rows_kernel(
        const int* __restrict__ cnt, const float* __restrict__ diag,
        const int* __restrict__ pairs, float* __restrict__ L) {
    __shared__ int   ec[CAP + 1];
    __shared__ float ev[CAP + 1];

    const int row = blockIdx.x;
    const int tid = threadIdx.x;

    int k = cnt[row];                      // same-address load -> broadcast
    if (k > CAP) k = CAP;
    if (tid < k) {
        const int* p = pairs + (size_t)(row * CAP + tid) * 2;
        ec[tid] = p[0];
        ev[tid] = ((const float*)p)[1];
    }
    if (tid == k) { ec[tid] = row; ev[tid] = diag[row]; }  // diagonal entry
    __syncthreads();

    float o[32];
#pragma unroll
    for (int i = 0; i < 32; ++i) o[i] = 0.0f;

    const int kk = k + 1;
#define CASE_(i) case i: o[i] += v; break;
    for (int e = 0; e < kk; ++e) {
        const int   c = ec[e];             // uniform LDS broadcast
        const float v = ev[e];
        if (((c >> 2) & 255) == tid) {     // exactly one owner thread
            const int idx = ((c >> 10) << 2) | (c & 3);   // static 0..31
            switch (idx) {
                CASE_(0)  CASE_(1)  CASE_(2)  CASE_(3)
                CASE_(4)  CASE_(5)  CASE_(6)  CASE_(7)
                CASE_(8)  CASE_(9)  CASE_(10) CASE_(11)
                CASE_(12) CASE_(13) CASE_(14) CASE_(15)
                CASE_(16) CASE_(17) CASE_(18) CASE_(19)
                CASE_(20) CASE_(21) CASE_(22) CASE_(23)
                CASE_(24) CASE_(25) CASE_(26) CASE_(27)
                CASE_(28) CASE_(29) CASE_(30) CASE_(31)
            }
        }
    }
#undef CASE_

    // single coalesced store pass, NONTEMPORAL (L2-bypass streaming stores)
    float* rowp = L + (size_t)row * 8192;
#pragma unroll
    for (int g = 0; g < 8; ++g) {
        v4f t;
        t[0] = o[4 * g + 0]; t[1] = o[4 * g + 1];
        t[2] = o[4 * g + 2]; t[3] = o[4 * g + 3];
        __builtin_nontemporal_store(t, (v4f*)(rowp + 4 * (tid + (g << 8))));
    }
}

// ---- generic fallback (N != 8192 or ws too small): memset + scatter ----
__global__ __launch_bounds__(256) void corner_scatter_kernel(
        const float* __restrict__ V, const int* __restrict__ Fw,
        float* __restrict__ L, int nF, int N) {
    const int g = blockIdx.x * 256 + threadIdx.x;
    if (g >= nF * 3) return;
    const int f = g / 3;
    const int t = g - f * 3;

    const bool is64 = (Fw[1] == 0) && (Fw[3] == 0) && (Fw[5] == 0) &&
                      (Fw[7] == 0) && (Fw[9] == 0) && (Fw[11] == 0);
    int i0, i1, i2;
    read_face(Fw, f, is64, i0, i1, i2);

    float c0, c1, c2;
    cot_weights(V, i0, i1, i2, c0, c1, c2);

    const float num = (t == 0) ? c0 : (t == 1) ? c1 : c2;
    const int r = (t == 0) ? i1 : (t == 1) ? i2 : i0;
    const int c = (t == 0) ? i2 : (t == 1) ? i0 : i1;

    const size_t n = (size_t)N;
    atomicAdd(&L[(size_t)r * n + c], -num);
    atomicAdd(&L[(size_t)c * n + r], -num);
    atomicAdd(&L[(size_t)r * n + r],  num);
    atomicAdd(&L[(size_t)c * n + c],  num);
}

extern "C" void kernel_launch(void* const* d_in, const int* in_sizes, int n_in,
                              void* d_out, int out_size, void* d_ws, size_t ws_size,
                              hipStream_t stream) {
    const float* V = (const float*)d_in[0];
    const int* Fw  = (const int*)d_in[1];
    float* L       = (float*)d_out;

    const int N  = in_sizes[0] / 3;   // 8192 vertices
    const int nF = in_sizes[1] / 3;   // 16384 faces

    // ws words: cnt 8192 + diag 8192 + pairs 8192*CAP*2
    const size_t need_bytes = (size_t)(2 * 8192 + 8192 * CAP * 2) * 4;

    if (N == 8192 && ws_size >= need_bytes) {
        int*   cnt   = (int*)d_ws;
        float* diag  = (float*)((char*)d_ws + 8192 * 4);
        int*   pairs = (int*)((char*)d_ws + 2 * 8192 * 4);

        // node 1: zero cnt + diag (64KB)
        hipMemsetAsync(d_ws, 0, (size_t)(2 * 8192) * 4, stream);
        // node 2: bin (appends pairs; no need to pre-zero the pair region)
        bin_faces_kernel<<<(nF + 255) / 256, 256, 0, stream>>>(
            V, Fw, cnt, diag, pairs, nF);
        // node 3: fill (one row per block, nontemporal streaming stores)
        fill_rows_kernel<<<8192, 256, 0, stream>>>(cnt, diag, pairs, L);
    } else {
        hipMemsetAsync(d_out, 0, (size_t)out_size * sizeof(float), stream);
        const int total = nF * 3;
        corner_scatter_kernel<<<(total + 255) / 256, 256, 0, stream>>>(V, Fw, L, nF, N);
    }
}

// Round 11
// 50.869 us; speedup vs baseline: 1.4480x; 1.4480x over previous
//
#include <hip/hip_runtime.h>
#include <math.h>

// L = diag((W+W^T).sum(1)) - (W+W^T), cotangent weights per face.
// BEST MEASURED STRUCTURE (R6 = 50.7us), reverted after R7-R10 alternatives
// all regressed:
//   node 1: hipMemsetAsync of the 256MB output (rocclr fill ~7.0 TB/s = the
//           best sustained writer on this chip; hand-written store kernels
//           plateau at ~5.4 TB/s across two independent structures)
//   node 2: corner-per-thread scatter (3 threads/face, 4 atomics each).
//           Floor = ~26-50MB of cold-line HBM RMW traffic ~ 5-8us.
// Structure floor ~ 38.4 (memset) + 2.5 (gap) + 8 (scatter) ~ 49us.

typedef float v4f __attribute__((ext_vector_type(4)));

__global__ __launch_bounds__(256) void corner_scatter_kernel(
        const float* __restrict__ V, const int* __restrict__ Fw,
        float* __restrict__ L, int nF, int N) {
    const int g = blockIdx.x * 256 + threadIdx.x;
    if (g >= nF * 3) return;

    const int f = g / 3;           // magic-mul division
    const int t = g - f * 3;       // corner 0/1/2

    // int64 vs int32 layout detection (little-endian high words all zero;
    // F values < 8192 so genuine-int32 false positive ~ (1/8192)^6)
    const bool is64 = (Fw[1] == 0) && (Fw[3] == 0) && (Fw[5] == 0) &&
                      (Fw[7] == 0) && (Fw[9] == 0) && (Fw[11] == 0);

    int i0, i1, i2;
    if (is64) { i0 = Fw[f * 6]; i1 = Fw[f * 6 + 2]; i2 = Fw[f * 6 + 4]; }
    else      { i0 = Fw[f * 3]; i1 = Fw[f * 3 + 1]; i2 = Fw[f * 3 + 2]; }

    // v1 = V[i0], v2 = V[i1], v3 = V[i2]  (V is 96KB -> L1/L2-hot)
    const float ax = V[i0 * 3 + 0], ay = V[i0 * 3 + 1], az = V[i0 * 3 + 2];
    const float bx = V[i1 * 3 + 0], by = V[i1 * 3 + 1], bz = V[i1 * 3 + 2];
    const float cx = V[i2 * 3 + 0], cy = V[i2 * 3 + 1], cz = V[i2 * 3 + 2];

    float dx, dy, dz, d2;
    dx = bx - cx; dy = by - cy; dz = bz - cz;
    d2 = dx * dx + dy * dy + dz * dz;
    const float l1 = (d2 > 0.0f) ? sqrtf(d2) : 0.0f;
    dx = cx - ax; dy = cy - ay; dz = cz - az;
    d2 = dx * dx + dy * dy + dz * dz;
    const float l2 = (d2 > 0.0f) ? sqrtf(d2) : 0.0f;
    dx = ax - bx; dy = ay - by; dz = az - bz;
    d2 = dx * dx + dy * dy + dz * dz;
    const float l3 = (d2 > 0.0f) ? sqrtf(d2) : 0.0f;

    const float sp = (l1 + l2 + l3) * 0.5f;
    const float s  = sp * (sp - l1) * (sp - l2) * (sp - l3);
    const float A  = (s > 0.0f) ? 2.0f * sqrtf(s) : 1.0f;

    const float q1 = l1 * l1, q2 = l2 * l2, q3 = l3 * l3;
    const float num = (t == 0) ? (q2 + q3 - q1)
                    : (t == 1) ? (q1 + q3 - q2)
                               : (q1 + q2 - q3);
    const int r = (t == 0) ? i1 : (t == 1) ? i2 : i0;
    const int c = (t == 0) ? i2 : (t == 1) ? i0 : i1;
    const float v = (num / A) * 0.25f;

    const size_t n = (size_t)N;
    atomicAdd(&L[(size_t)r * n + c], -v);
    atomicAdd(&L[(size_t)c * n + r], -v);
    atomicAdd(&L[(size_t)r * n + r],  v);
    atomicAdd(&L[(size_t)c * n + c],  v);
}

extern "C" void kernel_launch(void* const* d_in, const int* in_sizes, int n_in,
                              void* d_out, int out_size, void* d_ws, size_t ws_size,
                              hipStream_t stream) {
    const float* V = (const float*)d_in[0];
    const int* Fw  = (const int*)d_in[1];
    float* L       = (float*)d_out;

    const int N  = in_sizes[0] / 3;   // 8192 vertices
    const int nF = in_sizes[1] / 3;   // 16384 faces

    // Node 1: zero the output at fill rate (~7 TB/s, the structural floor)
    hipMemsetAsync(d_out, 0, (size_t)out_size * sizeof(float), stream);

    // Node 2: corner-per-thread scatter (3*nF threads, 4 atomics each)
    const int total = nF * 3;
    const int block = 256;
    corner_scatter_kernel<<<(total + block - 1) / block, block, 0, stream>>>(
        V, Fw, L, nF, N);
}